// Round 1
// baseline (325.623 us; speedup 1.0000x reference)
//
#include <hip/hip_runtime.h>
#include <hip/hip_bf16.h>
#include <math.h>

#define B_TOTAL 16384
#define D 64
#define L_U 50
#define N_F 32
#define L_I 50

// ---------------------------------------------------------------------------
// Setup: u[0..63]=W1@W3, u[64..]=W2@W3, u[128..]=W4@W6, u[192..]=W5@W6,
//        u[256..]=W7@W9, u[320..]=W8@W9   (each Wm is [64,64] row-major,
//        Wv is [64,1]; (q@Wm)@Wv == q . (Wm@Wv))
// ---------------------------------------------------------------------------
__global__ void graphrec_setup(const float* __restrict__ W1, const float* __restrict__ W2,
                               const float* __restrict__ W3, const float* __restrict__ W4,
                               const float* __restrict__ W5, const float* __restrict__ W6,
                               const float* __restrict__ W7, const float* __restrict__ W8,
                               const float* __restrict__ W9, float* __restrict__ u) {
    int t = threadIdx.x;           // 0..383
    int w = t >> 6;                // which of 6 vectors
    int d = t & 63;
    const float* Wm;
    const float* Wv;
    switch (w) {
        case 0: Wm = W1; Wv = W3; break;
        case 1: Wm = W2; Wv = W3; break;
        case 2: Wm = W4; Wv = W6; break;
        case 3: Wm = W5; Wv = W6; break;
        case 4: Wm = W7; Wv = W9; break;
        default: Wm = W8; Wv = W9; break;
    }
    float s = 0.f;
    #pragma unroll
    for (int j = 0; j < D; ++j) s = fmaf(Wm[d * D + j], Wv[j], s);
    u[w * D + d] = s;
}

// ---------------------------------------------------------------------------
// Main kernel: one wave (64 lanes) per batch element; lane == embedding dim.
// ---------------------------------------------------------------------------
__device__ __forceinline__ float wave_sum(float p) {
    #pragma unroll
    for (int off = 32; off; off >>= 1) p += __shfl_xor(p, off);
    return p;
}

// Online-softmax attention. Returns the per-lane (per-dim) attended output.
// cq: wave-uniform query score term; table: embedding table to gather from;
// u2: per-lane (Wk@Wa)[lane]; wa: per-lane Wa[lane];
// idxreg/rreg: lane l (< L) holds neighbor index / rating for slot l.
template <int L, bool HAS_R>
__device__ __forceinline__ float attn(float cq, const float* __restrict__ table,
                                      float u2, float wa, int idxreg, float rreg,
                                      int lane) {
    float m = -__builtin_inff();
    float s = 0.f;
    float acc = 0.f;
    #pragma unroll
    for (int l = 0; l < L; ++l) {
        int idx = __shfl(idxreg, l);                 // readlane (l is constant)
        float n = table[(size_t)idx * D + lane];     // coalesced 256B row gather
        float v = u2;
        if (HAS_R) {
            float r = __shfl(rreg, l);
            v = fmaf(r, wa, u2);
        }
        float sc = cq + wave_sum(n * v);
        float mn = fmaxf(m, sc);
        float a = __expf(m - mn);     // first iter: exp(-inf) = 0
        float e = __expf(sc - mn);
        s = fmaf(s, a, e);
        acc = acc * a + e * n;
        m = mn;
    }
    return acc / s;
}

__global__ __launch_bounds__(256) void graphrec_fwd(
        const int* __restrict__ user_ids, const int* __restrict__ item_ids,
        const int* __restrict__ uh_items, const float* __restrict__ uh_rat,
        const int* __restrict__ ufriends,
        const int* __restrict__ ih_users, const float* __restrict__ ih_rat,
        const float* __restrict__ eu, const float* __restrict__ ei,
        const float* __restrict__ W3, const float* __restrict__ W6,
        const float* __restrict__ W9,
        const float* __restrict__ fc1w, const float* __restrict__ fc1b,
        const float* __restrict__ fc2w, const float* __restrict__ fc2b,
        const float* __restrict__ u, float* __restrict__ out) {
    const int lane = threadIdx.x & 63;
    const int b = blockIdx.x * 4 + (threadIdx.x >> 6);

    // Per-lane neighbor metadata (lane l holds slot l).
    int idxA = 0, idxB = 0, idxC = 0;
    float rA = 0.f, rC = 0.f;
    if (lane < L_U) {
        idxA = uh_items[b * L_U + lane];
        rA   = uh_rat[b * L_U + lane];
        idxC = ih_users[b * L_I + lane];
        rC   = ih_rat[b * L_I + lane];
    }
    if (lane < N_F) idxB = ufriends[b * N_F + lane];

    const int uid = user_ids[b];
    const int iid = item_ids[b];
    const float qu = eu[(size_t)uid * D + lane];
    const float qi = ei[(size_t)iid * D + lane];

    const float u1a = u[lane],       u2a = u[64 + lane];
    const float u1b = u[128 + lane], u2b = u[192 + lane];
    const float u1c = u[256 + lane], u2c = u[320 + lane];
    const float wa = W3[lane], wb = W6[lane], wc = W9[lane];

    const float cqa = wave_sum(qu * u1a);
    const float cqb = wave_sum(qu * u1b);
    const float cqc = wave_sum(qi * u1c);

    const float accA = attn<L_U, true >(cqa, ei, u2a, wa, idxA, rA, lane);
    const float accB = attn<N_F, false>(cqb, eu, u2b, wb, idxB, 0.f, lane);
    const float accC = attn<L_I, true >(cqc, eu, u2c, wc, idxC, rC, lane);

    const float uf  = qu + accA + accB;   // user_emb_final[lane]
    const float itf = qi + accC;          // item_emb_final[lane]

    // MLP: h_j = relu(fc1b[j] + sum_k c_k * fc1w[k*64+j]), c = [uf ; itf]
    float h = fc1b[lane];
    #pragma unroll
    for (int k = 0; k < D; ++k) {
        float c = __shfl(uf, k);
        h = fmaf(c, fc1w[k * D + lane], h);
    }
    #pragma unroll
    for (int k = 0; k < D; ++k) {
        float c = __shfl(itf, k);
        h = fmaf(c, fc1w[(D + k) * D + lane], h);
    }
    h = fmaxf(h, 0.f);
    float o = wave_sum(h * fc2w[lane]);
    if (lane == 0) out[b] = o + fc2b[0];
}

extern "C" void kernel_launch(void* const* d_in, const int* in_sizes, int n_in,
                              void* d_out, int out_size, void* d_ws, size_t ws_size,
                              hipStream_t stream) {
    const int*   user_ids = (const int*)d_in[0];
    const int*   item_ids = (const int*)d_in[1];
    const int*   uh_items = (const int*)d_in[2];
    const float* uh_rat   = (const float*)d_in[3];
    const int*   ufriends = (const int*)d_in[4];
    const int*   ih_users = (const int*)d_in[5];
    const float* ih_rat   = (const float*)d_in[6];
    const float* eu       = (const float*)d_in[7];
    const float* ei       = (const float*)d_in[8];
    const float* W1 = (const float*)d_in[9];
    const float* W2 = (const float*)d_in[10];
    const float* W3 = (const float*)d_in[11];
    const float* W4 = (const float*)d_in[12];
    const float* W5 = (const float*)d_in[13];
    const float* W6 = (const float*)d_in[14];
    const float* W7 = (const float*)d_in[15];
    const float* W8 = (const float*)d_in[16];
    const float* W9 = (const float*)d_in[17];
    const float* fc1w = (const float*)d_in[18];
    const float* fc1b = (const float*)d_in[19];
    const float* fc2w = (const float*)d_in[20];
    const float* fc2b = (const float*)d_in[21];
    float* out = (float*)d_out;
    float* u   = (float*)d_ws;   // 6 * 64 floats = 1536 B

    graphrec_setup<<<1, 384, 0, stream>>>(W1, W2, W3, W4, W5, W6, W7, W8, W9, u);
    graphrec_fwd<<<B_TOTAL / 4, 256, 0, stream>>>(
        user_ids, item_ids, uh_items, uh_rat, ufriends, ih_users, ih_rat,
        eu, ei, W3, W6, W9, fc1w, fc1b, fc2w, fc2b, u, out);
}

// Round 3
// 242.998 us; speedup vs baseline: 1.3400x; 1.3400x over previous
//
#include <hip/hip_runtime.h>
#include <hip/hip_bf16.h>
#include <math.h>

#define B_TOTAL 16384
#define D 64
#define L_U 50
#define N_F 32
#define L_I 50
#define STRIDE 65   // 64 + 1 pad: dot-phase bank = (lane+d)%32 -> 2-way (free)

// ---------------------------------------------------------------------------
// Setup: u[0..63]=W1@W3, u[64..]=W2@W3, u[128..]=W4@W6, u[192..]=W5@W6,
//        u[256..]=W7@W9, u[320..]=W8@W9
// ---------------------------------------------------------------------------
__global__ void graphrec_setup(const float* __restrict__ W1, const float* __restrict__ W2,
                               const float* __restrict__ W3, const float* __restrict__ W4,
                               const float* __restrict__ W5, const float* __restrict__ W6,
                               const float* __restrict__ W7, const float* __restrict__ W8,
                               const float* __restrict__ W9, float* __restrict__ u) {
    int t = threadIdx.x;           // 0..383
    int w = t >> 6;                // which of 6 vectors
    int d = t & 63;
    const float* Wm;
    const float* Wv;
    switch (w) {
        case 0: Wm = W1; Wv = W3; break;
        case 1: Wm = W2; Wv = W3; break;
        case 2: Wm = W4; Wv = W6; break;
        case 3: Wm = W5; Wv = W6; break;
        case 4: Wm = W7; Wv = W9; break;
        default: Wm = W8; Wv = W9; break;
    }
    float s = 0.f;
    #pragma unroll
    for (int j = 0; j < D; ++j) s = fmaf(Wm[d * D + j], Wv[j], s);
    u[w * D + d] = s;
}

// ---------------------------------------------------------------------------
// Wave-wide reductions (one-shot per attention, not per neighbor)
// ---------------------------------------------------------------------------
__device__ __forceinline__ float wave_sum(float p) {
    #pragma unroll
    for (int off = 32; off; off >>= 1) p += __shfl_xor(p, off);
    return p;
}
__device__ __forceinline__ float wave_max(float p) {
    #pragma unroll
    for (int off = 32; off; off >>= 1) p = fmaxf(p, __shfl_xor(p, off));
    return p;
}

// ---------------------------------------------------------------------------
// Two-pass attention through a wave-private LDS tile.
//   cq    : wave-uniform query score term  q.(Wq@Wa)
//   table : embedding table for neighbor gathers
//   u2g   : global ptr to (Wk@Wa)[64]  (wave-uniform scalar loads in dot phase)
//   wag   : global ptr to Wa[64]       (scalar loads, only if HAS_R)
//   idxreg: lane l (< L) holds neighbor index for slot l
//   r     : lane l (< L) holds rating for slot l
//   buf   : wave-private LDS region, L_U*STRIDE floats
// ---------------------------------------------------------------------------
template <int L, bool HAS_R>
__device__ __forceinline__ float attn_lds(float cq, const float* __restrict__ table,
                                          const float* __restrict__ u2g,
                                          const float* __restrict__ wag,
                                          int idxreg, float r, int lane,
                                          float* buf) {
    // Previous phase's ds_reads of this buffer must drain before DMA overwrites.
    asm volatile("s_waitcnt lgkmcnt(0)" ::: "memory");

    // ---- stage L rows (256B each, coalesced) global -> LDS, fire-and-forget
    #pragma unroll
    for (int l = 0; l < L; ++l) {
        int idx = __shfl(idxreg, l);                       // readlane (l const)
        const float* gp = table + (size_t)idx * D + lane;  // per-lane element
        __builtin_amdgcn_global_load_lds(
            (const __attribute__((address_space(1))) void*)gp,
            (__attribute__((address_space(3))) void*)(buf + l * STRIDE),
            4, 0, 0);                                      // lands at base+lane*4
    }
    asm volatile("s_waitcnt vmcnt(0)" ::: "memory");

    // ---- dot phase: lane = neighbor; u2g/wag are wave-uniform scalar loads
    float dotU = 0.f, dotW = 0.f;
    const float* row = buf + lane * STRIDE;
    #pragma unroll
    for (int d = 0; d < D; ++d) {
        float n = row[d];                 // bank (lane+d)%32 -> 2-way, free
        dotU = fmaf(n, u2g[d], dotU);
        if (HAS_R) dotW = fmaf(n, wag[d], dotW);
    }
    float sc = cq + dotU;
    if (HAS_R) sc = fmaf(r, dotW, sc);
    sc = (lane < L) ? sc : -1e30f;        // mask tail lanes (stale LDS rows)

    // ---- softmax across lanes: ONE exp per attention
    float m = wave_max(sc);
    float e = __expf(sc - m);             // tail lanes -> ~0
    float s = wave_sum(e);
    float w = e / s;

    // ---- weighted sum: lane = dim
    float acc = 0.f;
    #pragma unroll
    for (int l = 0; l < L; ++l) {
        float wl = __shfl(w, l);          // readlane
        acc = fmaf(wl, buf[l * STRIDE + lane], acc);
    }
    return acc;
}

__global__ __launch_bounds__(256) void graphrec_fwd(
        const int* __restrict__ user_ids, const int* __restrict__ item_ids,
        const int* __restrict__ uh_items, const float* __restrict__ uh_rat,
        const int* __restrict__ ufriends,
        const int* __restrict__ ih_users, const float* __restrict__ ih_rat,
        const float* __restrict__ eu, const float* __restrict__ ei,
        const float* __restrict__ W3, const float* __restrict__ W6,
        const float* __restrict__ W9,
        const float* __restrict__ fc1w, const float* __restrict__ fc1b,
        const float* __restrict__ fc2w, const float* __restrict__ fc2b,
        const float* __restrict__ u, float* __restrict__ out) {
    __shared__ float smem[4 * L_U * STRIDE];          // 52 KB: 3 blocks/CU
    const int lane = threadIdx.x & 63;
    const int wv = threadIdx.x >> 6;
    const int b = blockIdx.x * 4 + wv;
    float* buf = smem + wv * (L_U * STRIDE);

    // Per-lane neighbor metadata (lane l holds slot l).
    int idxA = 0, idxB = 0, idxC = 0;
    float rA = 0.f, rC = 0.f;
    if (lane < L_U) {
        idxA = uh_items[b * L_U + lane];
        rA   = uh_rat[b * L_U + lane];
        idxC = ih_users[b * L_I + lane];
        rC   = ih_rat[b * L_I + lane];
    }
    if (lane < N_F) idxB = ufriends[b * N_F + lane];

    const int uid = user_ids[b];
    const int iid = item_ids[b];
    const float qu = eu[(size_t)uid * D + lane];
    const float qi = ei[(size_t)iid * D + lane];

    // cq = q . (Wq@Wa) for each attention
    const float cqa = wave_sum(qu * u[lane]);
    const float cqb = wave_sum(qu * u[128 + lane]);
    const float cqc = wave_sum(qi * u[256 + lane]);

    const float accA = attn_lds<L_U, true >(cqa, ei, u + 64,  W3, idxA, rA, lane, buf);
    const float accB = attn_lds<N_F, false>(cqb, eu, u + 192, W6, idxB, 0.f, lane, buf);
    const float accC = attn_lds<L_I, true >(cqc, eu, u + 320, W9, idxC, rC, lane, buf);

    const float uf  = qu + accA + accB;   // user_emb_final[lane]
    const float itf = qi + accC;          // item_emb_final[lane]

    // MLP: h_j = relu(fc1b[j] + sum_k c_k * fc1w[k*64+j]), c = [uf ; itf]
    float h = fc1b[lane];
    #pragma unroll
    for (int k = 0; k < D; ++k) {
        float c = __shfl(uf, k);
        h = fmaf(c, fc1w[k * D + lane], h);
    }
    #pragma unroll
    for (int k = 0; k < D; ++k) {
        float c = __shfl(itf, k);
        h = fmaf(c, fc1w[(D + k) * D + lane], h);
    }
    h = fmaxf(h, 0.f);
    float o = wave_sum(h * fc2w[lane]);
    if (lane == 0) out[b] = o + fc2b[0];
}

extern "C" void kernel_launch(void* const* d_in, const int* in_sizes, int n_in,
                              void* d_out, int out_size, void* d_ws, size_t ws_size,
                              hipStream_t stream) {
    const int*   user_ids = (const int*)d_in[0];
    const int*   item_ids = (const int*)d_in[1];
    const int*   uh_items = (const int*)d_in[2];
    const float* uh_rat   = (const float*)d_in[3];
    const int*   ufriends = (const int*)d_in[4];
    const int*   ih_users = (const int*)d_in[5];
    const float* ih_rat   = (const float*)d_in[6];
    const float* eu       = (const float*)d_in[7];
    const float* ei       = (const float*)d_in[8];
    const float* W1 = (const float*)d_in[9];
    const float* W2 = (const float*)d_in[10];
    const float* W3 = (const float*)d_in[11];
    const float* W4 = (const float*)d_in[12];
    const float* W5 = (const float*)d_in[13];
    const float* W6 = (const float*)d_in[14];
    const float* W7 = (const float*)d_in[15];
    const float* W8 = (const float*)d_in[16];
    const float* W9 = (const float*)d_in[17];
    const float* fc1w = (const float*)d_in[18];
    const float* fc1b = (const float*)d_in[19];
    const float* fc2w = (const float*)d_in[20];
    const float* fc2b = (const float*)d_in[21];
    float* out = (float*)d_out;
    float* u   = (float*)d_ws;   // 6 * 64 floats = 1536 B

    graphrec_setup<<<1, 384, 0, stream>>>(W1, W2, W3, W4, W5, W6, W7, W8, W9, u);
    graphrec_fwd<<<B_TOTAL / 4, 256, 0, stream>>>(
        user_ids, item_ids, uh_items, uh_rat, ufriends, ih_users, ih_rat,
        eu, ei, W3, W6, W9, fc1w, fc1b, fc2w, fc2b, u, out);
}

// Round 4
// 231.486 us; speedup vs baseline: 1.4067x; 1.0497x over previous
//
#include <hip/hip_runtime.h>
#include <hip/hip_bf16.h>
#include <math.h>

#define B_TOTAL 16384
#define D 64
#define L_U 50
#define N_F 32
#define L_I 50

// ---------------------------------------------------------------------------
// Setup: u[0..63]=W1@W3, u[64..]=W2@W3, u[128..]=W4@W6, u[192..]=W5@W6,
//        u[256..]=W7@W9, u[320..]=W8@W9
// ---------------------------------------------------------------------------
__global__ void graphrec_setup(const float* __restrict__ W1, const float* __restrict__ W2,
                               const float* __restrict__ W3, const float* __restrict__ W4,
                               const float* __restrict__ W5, const float* __restrict__ W6,
                               const float* __restrict__ W7, const float* __restrict__ W8,
                               const float* __restrict__ W9, float* __restrict__ u) {
    int t = threadIdx.x;           // 0..383
    int w = t >> 6;                // which of 6 vectors
    int d = t & 63;
    const float* Wm;
    const float* Wv;
    switch (w) {
        case 0: Wm = W1; Wv = W3; break;
        case 1: Wm = W2; Wv = W3; break;
        case 2: Wm = W4; Wv = W6; break;
        case 3: Wm = W5; Wv = W6; break;
        case 4: Wm = W7; Wv = W9; break;
        default: Wm = W8; Wv = W9; break;
    }
    float s = 0.f;
    #pragma unroll
    for (int j = 0; j < D; ++j) s = fmaf(Wm[d * D + j], Wv[j], s);
    u[w * D + d] = s;
}

__device__ __forceinline__ float wave_sum(float p) {
    #pragma unroll
    for (int off = 32; off; off >>= 1) p += __shfl_xor(p, off);
    return p;
}
__device__ __forceinline__ float wave_max(float p) {
    #pragma unroll
    for (int off = 32; off; off >>= 1) p = fmaxf(p, __shfl_xor(p, off));
    return p;
}

// ---------------------------------------------------------------------------
// Two-pass attention through a pad-free wave-private LDS tile (rows = 64 f32,
// 256 B). Staging: 16 B global_load_lds = 4 rows / instruction. Dot phase:
// float4 LDS reads with per-lane chunk rotation (full-BW bank spread);
// coefficient vectors come from block-shared LDS (same-address broadcast).
//   cv4    : block-shared float4 LDS with [u2 | Wa] vectors
//   u2o,wao: float4 offsets of (Wk@Wa) and Wa inside cv4
// ---------------------------------------------------------------------------
template <int L, bool HAS_R>
__device__ __forceinline__ float attn2(float cq, const float* __restrict__ table,
                                       const float4* cv4, int u2o, int wao,
                                       int idxreg, float r, int lane,
                                       float* tile) {
    // Previous phase's ds_reads of this tile must drain before DMA overwrites.
    asm volatile("s_waitcnt lgkmcnt(0)" ::: "memory");

    const int sub = lane >> 4;      // row within 4-row group
    const int chunk = lane & 15;    // 16 B chunk within row

    // ---- stage: 4 rows (1 KiB) per global_load_lds_dwordx4
    #pragma unroll
    for (int g = 0; g < (L + 3) / 4; ++g) {
        const int rg = (4 * g + 4 <= L) ? 4 * g : (L - 4);  // tail overlaps, same data
        int idx = __shfl(idxreg, rg + sub);
        const float* gp = table + (size_t)idx * D + (chunk << 2);
        __builtin_amdgcn_global_load_lds(
            (const __attribute__((address_space(1))) void*)gp,
            (__attribute__((address_space(3))) void*)(tile + rg * D),
            16, 0, 0);              // lane lands at base + lane*16
    }
    asm volatile("s_waitcnt vmcnt(0)" ::: "memory");

    // ---- dot phase: lane = neighbor, float4 chunks with rotation
    const float4* tile4 = (const float4*)tile;
    const int rbase = ((lane < L) ? lane : (L - 1)) * (D / 4);
    float dotU = 0.f, dotW = 0.f;
    #pragma unroll
    for (int j = 0; j < D / 4; ++j) {
        const int c = (lane + j) & 15;
        float4 n = tile4[rbase + c];
        float4 uu = cv4[u2o + c];
        dotU = fmaf(n.x, uu.x, fmaf(n.y, uu.y, fmaf(n.z, uu.z, fmaf(n.w, uu.w, dotU))));
        if (HAS_R) {
            float4 ww = cv4[wao + c];
            dotW = fmaf(n.x, ww.x, fmaf(n.y, ww.y, fmaf(n.z, ww.z, fmaf(n.w, ww.w, dotW))));
        }
    }
    float sc = cq + dotU;
    if (HAS_R) sc = fmaf(r, dotW, sc);
    sc = (lane < L) ? sc : -1e30f;

    // ---- softmax across lanes: one exp per attention
    float m = wave_max(sc);
    float e = __expf(sc - m);
    float s = wave_sum(e);
    float w = e / s;

    // ---- weighted sum: lane = dim (bank = lane%32, 2-way, free)
    float acc = 0.f;
    #pragma unroll
    for (int l = 0; l < L; ++l) {
        float wl = __shfl(w, l);    // readlane
        acc = fmaf(wl, tile[l * D + lane], acc);
    }
    return acc;
}

__global__ __launch_bounds__(256) void graphrec_fwd(
        const int* __restrict__ user_ids, const int* __restrict__ item_ids,
        const int* __restrict__ uh_items, const float* __restrict__ uh_rat,
        const int* __restrict__ ufriends,
        const int* __restrict__ ih_users, const float* __restrict__ ih_rat,
        const float* __restrict__ eu, const float* __restrict__ ei,
        const float* __restrict__ W3, const float* __restrict__ W6,
        const float* __restrict__ W9,
        const float* __restrict__ fc1w, const float* __restrict__ fc1b,
        const float* __restrict__ fc2w, const float* __restrict__ fc2b,
        const float* __restrict__ u, float* __restrict__ out) {
    // 4 wave tiles (50x64 f32 each) + 6 coefficient vectors = 52736 B -> 3 blocks/CU
    __shared__ __align__(16) float smem[4 * L_U * D + 6 * D];
    float* cvec = smem + 4 * L_U * D;

    // Stage [u2a|W3|u2b|W6|u2c|W9] into block-shared LDS (broadcast reads later).
    for (int i = threadIdx.x; i < 6 * D; i += 256) {
        int seg = i >> 6, off = i & 63;
        float v;
        switch (seg) {
            case 0: v = u[64 + off];  break;   // u2a = W2@W3
            case 1: v = W3[off];      break;
            case 2: v = u[192 + off]; break;   // u2b = W5@W6
            case 3: v = W6[off];      break;
            case 4: v = u[320 + off]; break;   // u2c = W8@W9
            default: v = W9[off];     break;
        }
        cvec[i] = v;
    }
    __syncthreads();
    const float4* cv4 = (const float4*)cvec;

    const int lane = threadIdx.x & 63;
    const int wv = threadIdx.x >> 6;
    const int b = blockIdx.x * 4 + wv;
    float* tile = smem + wv * (L_U * D);

    // Per-lane neighbor metadata (lane l holds slot l).
    int idxA = 0, idxB = 0, idxC = 0;
    float rA = 0.f, rC = 0.f;
    if (lane < L_U) {
        idxA = uh_items[b * L_U + lane];
        rA   = uh_rat[b * L_U + lane];
        idxC = ih_users[b * L_I + lane];
        rC   = ih_rat[b * L_I + lane];
    }
    if (lane < N_F) idxB = ufriends[b * N_F + lane];

    const int uid = user_ids[b];
    const int iid = item_ids[b];
    const float qu = eu[(size_t)uid * D + lane];
    const float qi = ei[(size_t)iid * D + lane];

    // cq = q . (Wq@Wa) for each attention
    const float cqa = wave_sum(qu * u[lane]);
    const float cqb = wave_sum(qu * u[128 + lane]);
    const float cqc = wave_sum(qi * u[256 + lane]);

    const float accA = attn2<L_U, true >(cqa, ei, cv4,  0, 16, idxA, rA, lane, tile);
    const float accB = attn2<N_F, false>(cqb, eu, cv4, 32, 48, idxB, 0.f, lane, tile);
    const float accC = attn2<L_I, true >(cqc, eu, cv4, 64, 80, idxC, rC, lane, tile);

    const float uf  = qu + accA + accB;   // user_emb_final[lane]
    const float itf = qi + accC;          // item_emb_final[lane]

    // MLP: h_j = relu(fc1b[j] + sum_k c_k * fc1w[k*64+j]), c = [uf ; itf]
    float h = fc1b[lane];
    #pragma unroll
    for (int k = 0; k < D; ++k) {
        float c = __shfl(uf, k);
        h = fmaf(c, fc1w[k * D + lane], h);
    }
    #pragma unroll
    for (int k = 0; k < D; ++k) {
        float c = __shfl(itf, k);
        h = fmaf(c, fc1w[(D + k) * D + lane], h);
    }
    h = fmaxf(h, 0.f);
    float o = wave_sum(h * fc2w[lane]);
    if (lane == 0) out[b] = o + fc2b[0];
}

extern "C" void kernel_launch(void* const* d_in, const int* in_sizes, int n_in,
                              void* d_out, int out_size, void* d_ws, size_t ws_size,
                              hipStream_t stream) {
    const int*   user_ids = (const int*)d_in[0];
    const int*   item_ids = (const int*)d_in[1];
    const int*   uh_items = (const int*)d_in[2];
    const float* uh_rat   = (const float*)d_in[3];
    const int*   ufriends = (const int*)d_in[4];
    const int*   ih_users = (const int*)d_in[5];
    const float* ih_rat   = (const float*)d_in[6];
    const float* eu       = (const float*)d_in[7];
    const float* ei       = (const float*)d_in[8];
    const float* W1 = (const float*)d_in[9];
    const float* W2 = (const float*)d_in[10];
    const float* W3 = (const float*)d_in[11];
    const float* W4 = (const float*)d_in[12];
    const float* W5 = (const float*)d_in[13];
    const float* W6 = (const float*)d_in[14];
    const float* W7 = (const float*)d_in[15];
    const float* W8 = (const float*)d_in[16];
    const float* W9 = (const float*)d_in[17];
    const float* fc1w = (const float*)d_in[18];
    const float* fc1b = (const float*)d_in[19];
    const float* fc2w = (const float*)d_in[20];
    const float* fc2b = (const float*)d_in[21];
    float* out = (float*)d_out;
    float* u   = (float*)d_ws;   // 6 * 64 floats = 1536 B

    graphrec_setup<<<1, 384, 0, stream>>>(W1, W2, W3, W4, W5, W6, W7, W8, W9, u);
    graphrec_fwd<<<B_TOTAL / 4, 256, 0, stream>>>(
        user_ids, item_ids, uh_items, uh_rat, ufriends, ih_users, ih_rat,
        eu, ei, W3, W6, W9, fc1w, fc1b, fc2w, fc2b, u, out);
}

// Round 5
// 227.260 us; speedup vs baseline: 1.4328x; 1.0186x over previous
//
#include <hip/hip_runtime.h>
#include <hip/hip_bf16.h>
#include <math.h>

#define B_TOTAL 16384
#define D 64
#define L_U 50
#define N_F 32
#define L_I 50
#define RSTRIDE 68   // row stride in floats (272 B): != 0 mod 128 B, so uniform-chunk
                     // b128 reads spread banks (2 dwords/bank per 16-lane group = free)

// ---------------------------------------------------------------------------
// Setup: u[0..63]=W1@W3, u[64..]=W2@W3, u[128..]=W4@W6, u[192..]=W5@W6,
//        u[256..]=W7@W9, u[320..]=W8@W9
// ---------------------------------------------------------------------------
__global__ void graphrec_setup(const float* __restrict__ W1, const float* __restrict__ W2,
                               const float* __restrict__ W3, const float* __restrict__ W4,
                               const float* __restrict__ W5, const float* __restrict__ W6,
                               const float* __restrict__ W7, const float* __restrict__ W8,
                               const float* __restrict__ W9, float* __restrict__ u) {
    int t = threadIdx.x;           // 0..383
    int w = t >> 6;                // which of 6 vectors
    int d = t & 63;
    const float* Wm;
    const float* Wv;
    switch (w) {
        case 0: Wm = W1; Wv = W3; break;
        case 1: Wm = W2; Wv = W3; break;
        case 2: Wm = W4; Wv = W6; break;
        case 3: Wm = W5; Wv = W6; break;
        case 4: Wm = W7; Wv = W9; break;
        default: Wm = W8; Wv = W9; break;
    }
    float s = 0.f;
    #pragma unroll
    for (int j = 0; j < D; ++j) s = fmaf(Wm[d * D + j], Wv[j], s);
    u[w * D + d] = s;
}

// ---------------------------------------------------------------------------
// Wave-wide reductions via DPP (VALU only, no LDS pipe). LLVM's reduction
// sequence: row_shr 1/2/4/8, row_bcast15 (rows 1,3), row_bcast31 (rows 2,3);
// lane 63 then holds the full-wave result; readlane(63) -> wave-uniform SGPR.
// update_dpp(old=identity,...): masked/invalid lanes contribute the identity.
// ---------------------------------------------------------------------------
__device__ __forceinline__ float wred_sum(float x) {
    float t;
    #define STEP_ADD(ctrl, rmask)                                                        \
        t = __int_as_float(__builtin_amdgcn_update_dpp(0, __float_as_int(x),             \
                                                       ctrl, rmask, 0xf, false));        \
        x = x + t;
    STEP_ADD(0x111, 0xf)   // row_shr:1
    STEP_ADD(0x112, 0xf)   // row_shr:2
    STEP_ADD(0x114, 0xf)   // row_shr:4
    STEP_ADD(0x118, 0xf)   // row_shr:8
    STEP_ADD(0x142, 0xa)   // row_bcast:15 -> rows 1,3
    STEP_ADD(0x143, 0xc)   // row_bcast:31 -> rows 2,3
    #undef STEP_ADD
    return __int_as_float(__builtin_amdgcn_readlane(__float_as_int(x), 63));
}
__device__ __forceinline__ float wred_max(float x) {
    const int NEG_INF = 0xFF800000;
    float t;
    #define STEP_MAX(ctrl, rmask)                                                        \
        t = __int_as_float(__builtin_amdgcn_update_dpp(NEG_INF, __float_as_int(x),       \
                                                       ctrl, rmask, 0xf, false));        \
        x = fmaxf(x, t);
    STEP_MAX(0x111, 0xf)
    STEP_MAX(0x112, 0xf)
    STEP_MAX(0x114, 0xf)
    STEP_MAX(0x118, 0xf)
    STEP_MAX(0x142, 0xa)
    STEP_MAX(0x143, 0xc)
    #undef STEP_MAX
    return __int_as_float(__builtin_amdgcn_readlane(__float_as_int(x), 63));
}

// ---------------------------------------------------------------------------
// Two-pass attention through a wave-private stride-68 LDS tile.
//   cq     : wave-uniform query score term  q.(Wq@Wa)
//   table  : embedding table for neighbor gathers
//   u2g/wag: global ptrs to (Wk@Wa)[64] / Wa[64] as float4 — loop index is
//            uniform, so these lower to scalar (SMEM) loads: zero LDS cost
//   idxreg : lane l (< L) holds neighbor index for slot l
//   r      : lane l (< L) holds rating for slot l
// ---------------------------------------------------------------------------
template <int L, bool HAS_R>
__device__ __forceinline__ float attn3(float cq, const float* __restrict__ table,
                                       const float4* __restrict__ u2g,
                                       const float4* __restrict__ wag,
                                       int idxreg, float r, int lane, float* tile) {
    // Previous phase's ds_reads of this tile must drain before DMA overwrites.
    asm volatile("s_waitcnt lgkmcnt(0)" ::: "memory");

    // ---- stage: one row (256 B) per 4 B-wide global_load_lds; uniform index
    //      via readlane -> scalar address math on the SALU.
    #pragma unroll
    for (int l = 0; l < L; ++l) {
        int idx = __builtin_amdgcn_readlane(idxreg, l);
        const float* gp = table + (size_t)(unsigned)idx * D + lane;
        __builtin_amdgcn_global_load_lds(
            (const __attribute__((address_space(1))) void*)gp,
            (__attribute__((address_space(3))) void*)(tile + l * RSTRIDE),
            4, 0, 0);                                    // lands at base+lane*4
    }
    asm volatile("s_waitcnt vmcnt(0)" ::: "memory");

    // ---- dot phase: lane = neighbor; uniform chunk j, bank-spread by stride-68
    const int rl = (lane < L) ? lane : (L - 1);          // tail lanes: broadcast row
    const float* row = tile + rl * RSTRIDE;
    float dotU = 0.f, dotW = 0.f;
    #pragma unroll
    for (int j = 0; j < D / 4; ++j) {
        float4 n = *(const float4*)(row + 4 * j);        // ds_read_b128, 2-way banks
        float4 uu = u2g[j];                              // scalar s_load
        dotU = fmaf(n.x, uu.x, fmaf(n.y, uu.y, fmaf(n.z, uu.z, fmaf(n.w, uu.w, dotU))));
        if (HAS_R) {
            float4 ww = wag[j];                          // scalar s_load
            dotW = fmaf(n.x, ww.x, fmaf(n.y, ww.y, fmaf(n.z, ww.z, fmaf(n.w, ww.w, dotW))));
        }
    }
    float sc = cq + dotU;
    if (HAS_R) sc = fmaf(r, dotW, sc);
    sc = (lane < L) ? sc : -1e30f;

    // ---- softmax across lanes: DPP reductions + one exp
    float m = wred_max(sc);
    float e = __expf(sc - m);
    float s = wred_sum(e);
    float w = e * (1.0f / s);

    // ---- weighted sum: lane = dim; bank = (4l+lane)%32 -> 2-way, free
    float acc = 0.f;
    #pragma unroll
    for (int l = 0; l < L; ++l) {
        float wl = __int_as_float(__builtin_amdgcn_readlane(__float_as_int(w), l));
        acc = fmaf(wl, tile[l * RSTRIDE + lane], acc);
    }
    return acc;
}

__global__ __launch_bounds__(256) void graphrec_fwd(
        const int* __restrict__ user_ids, const int* __restrict__ item_ids,
        const int* __restrict__ uh_items, const float* __restrict__ uh_rat,
        const int* __restrict__ ufriends,
        const int* __restrict__ ih_users, const float* __restrict__ ih_rat,
        const float* __restrict__ eu, const float* __restrict__ ei,
        const float* __restrict__ W3, const float* __restrict__ W6,
        const float* __restrict__ W9,
        const float* __restrict__ fc1w, const float* __restrict__ fc1b,
        const float* __restrict__ fc2w, const float* __restrict__ fc2b,
        const float* __restrict__ u, float* __restrict__ out) {
    // 4 wave tiles, 50 rows x 68 floats = 54400 B -> 3 blocks/CU. No barriers.
    __shared__ __align__(16) float smem[4 * L_U * RSTRIDE];
    const int lane = threadIdx.x & 63;
    const int wv = threadIdx.x >> 6;
    const int b = blockIdx.x * 4 + wv;
    float* tile = smem + wv * (L_U * RSTRIDE);

    // Per-lane neighbor metadata (lane l holds slot l).
    int idxA = 0, idxB = 0, idxC = 0;
    float rA = 0.f, rC = 0.f;
    if (lane < L_U) {
        idxA = uh_items[b * L_U + lane];
        rA   = uh_rat[b * L_U + lane];
        idxC = ih_users[b * L_I + lane];
        rC   = ih_rat[b * L_I + lane];
    }
    if (lane < N_F) idxB = ufriends[b * N_F + lane];

    const int uid = user_ids[b];
    const int iid = item_ids[b];
    const float qu = eu[(size_t)uid * D + lane];
    const float qi = ei[(size_t)iid * D + lane];

    // cq = q . (Wq@Wa) for each attention (DPP reduce -> uniform)
    const float cqa = wred_sum(qu * u[lane]);
    const float cqb = wred_sum(qu * u[128 + lane]);
    const float cqc = wred_sum(qi * u[256 + lane]);

    const float accA = attn3<L_U, true >(cqa, ei, (const float4*)(u + 64),
                                         (const float4*)W3, idxA, rA, lane, tile);
    const float accB = attn3<N_F, false>(cqb, eu, (const float4*)(u + 192),
                                         (const float4*)W6, idxB, 0.f, lane, tile);
    const float accC = attn3<L_I, true >(cqc, eu, (const float4*)(u + 320),
                                         (const float4*)W9, idxC, rC, lane, tile);

    const float uf  = qu + accA + accB;   // user_emb_final[lane]
    const float itf = qi + accC;          // item_emb_final[lane]

    // MLP: h_j = relu(fc1b[j] + sum_k c_k fc1w[k*64+j]); c_k via readlane (VALU),
    // fc1w reads are coalesced 256 B, L1-hot.
    float h = fc1b[lane];
    #pragma unroll
    for (int k = 0; k < D; ++k) {
        float c = __int_as_float(__builtin_amdgcn_readlane(__float_as_int(uf), k));
        h = fmaf(c, fc1w[k * D + lane], h);
    }
    #pragma unroll
    for (int k = 0; k < D; ++k) {
        float c = __int_as_float(__builtin_amdgcn_readlane(__float_as_int(itf), k));
        h = fmaf(c, fc1w[(D + k) * D + lane], h);
    }
    h = fmaxf(h, 0.f);
    float o = wred_sum(h * fc2w[lane]);
    if (lane == 0) out[b] = o + fc2b[0];
}

extern "C" void kernel_launch(void* const* d_in, const int* in_sizes, int n_in,
                              void* d_out, int out_size, void* d_ws, size_t ws_size,
                              hipStream_t stream) {
    const int*   user_ids = (const int*)d_in[0];
    const int*   item_ids = (const int*)d_in[1];
    const int*   uh_items = (const int*)d_in[2];
    const float* uh_rat   = (const float*)d_in[3];
    const int*   ufriends = (const int*)d_in[4];
    const int*   ih_users = (const int*)d_in[5];
    const float* ih_rat   = (const float*)d_in[6];
    const float* eu       = (const float*)d_in[7];
    const float* ei       = (const float*)d_in[8];
    const float* W1 = (const float*)d_in[9];
    const float* W2 = (const float*)d_in[10];
    const float* W3 = (const float*)d_in[11];
    const float* W4 = (const float*)d_in[12];
    const float* W5 = (const float*)d_in[13];
    const float* W6 = (const float*)d_in[14];
    const float* W7 = (const float*)d_in[15];
    const float* W8 = (const float*)d_in[16];
    const float* W9 = (const float*)d_in[17];
    const float* fc1w = (const float*)d_in[18];
    const float* fc1b = (const float*)d_in[19];
    const float* fc2w = (const float*)d_in[20];
    const float* fc2b = (const float*)d_in[21];
    float* out = (float*)d_out;
    float* u   = (float*)d_ws;   // 6 * 64 floats = 1536 B

    graphrec_setup<<<1, 384, 0, stream>>>(W1, W2, W3, W4, W5, W6, W7, W8, W9, u);
    graphrec_fwd<<<B_TOTAL / 4, 256, 0, stream>>>(
        user_ids, item_ids, uh_items, uh_rat, ufriends, ih_users, ih_rat,
        eu, ei, W3, W6, W9, fc1w, fc1b, fc2w, fc2b, u, out);
}